// Round 10
// baseline (12809.126 us; speedup 1.0000x reference)
//
#include <hip/hip_runtime.h>
#include <cstdint>
#include <cstddef>

// ---------------------------------------------------------------------------
// GRU persistent kernel, round 12: fused-gate blocks on the DMA-staged engine.
//   - R11 proved phases are aggregate-LLC-BW-bound (~8.2 TB/s). This round
//     cuts traffic 0.66x: 128 fused blocks compute Z+R+H~ for 16 cols from
//     ONE staged pass over X+Hc (3 MFMA streams per staged segment); phase B
//     stages RH once. Separate R-blocks are gone; Y keeps its own 64 blocks;
//     64 conv blocks only convert X.
//   - sync: hnf (128, H published), rhf (128, phase-A done / RH published),
//     xf (64, X converted), yf (64, Y done reading Hc). Two merged flag-waits
//     per step on the critical path. Grid slots kept for prologue only.
//   - R11 DMA staging engine (16KB/wave window, counted vmcnt, XOR swizzle)
//     unchanged.
// ---------------------------------------------------------------------------

#define T_ 512
#define B_ 64
#define I_ 1024
#define H_ 2048
#define NB 256
#define NTHREADS 512
#define GSTRIDE (NB * NTHREADS)

typedef __attribute__((ext_vector_type(8))) __bf16 bf16x8;
typedef __attribute__((ext_vector_type(2))) __bf16 bf16x2;
typedef __attribute__((ext_vector_type(4))) float f32x4;
typedef __attribute__((ext_vector_type(2))) float f32x2;

static constexpr unsigned SMEM_BYTES = 128 * 1024 + 20 * 1024;  // staging + reduce

// ---- workspace layout (bytes) ----
static constexpr size_t OFF_SLOT = 0;          // 256 x 64B (prologue only)
static constexpr size_t OFF_HNF  = 16384;      // 128 x 64B
static constexpr size_t OFF_RHF  = 24576;      // 128 x 64B
static constexpr size_t OFF_XF   = 32768;      // 64 x 64B
static constexpr size_t OFF_YF   = 36864;      // 64 x 64B
static constexpr size_t OFF_WXZT = 40960;
static constexpr size_t SZ_WXT   = (size_t)H_ * I_ * 2;    // 4 MiB
static constexpr size_t SZ_WHT   = (size_t)H_ * H_ * 2;    // 8 MiB
static constexpr size_t OFF_WXRT = OFF_WXZT + SZ_WXT;
static constexpr size_t OFF_WXHT = OFF_WXRT + SZ_WXT;
static constexpr size_t OFF_WHZT = OFF_WXHT + SZ_WXT;
static constexpr size_t OFF_WHRT = OFF_WHZT + SZ_WHT;
static constexpr size_t OFF_WHHT = OFF_WHRT + SZ_WHT;
static constexpr size_t OFF_WHQT = OFF_WHHT + SZ_WHT;      // N=1024,K=2048
static constexpr size_t OFF_XBF  = OFF_WHQT + SZ_WXT;
static constexpr size_t OFF_HBF  = OFF_XBF + (size_t)2 * B_ * I_ * 2;
static constexpr size_t OFF_RHBF = OFF_HBF + (size_t)2 * B_ * H_ * 2;
static constexpr size_t WS_NEEDED = OFF_RHBF + (size_t)B_ * H_ * 2;

__device__ __forceinline__ float fsigmoid(float x) { return 1.0f / (1.0f + __expf(-x)); }
__device__ __forceinline__ float ftanh(float x)    { return 2.0f / (1.0f + __expf(-2.0f * x)) - 1.0f; }

// ---- coherent (sc1 write-through) stores for cross-block data ----
__device__ __forceinline__ void cstore8(void* p, unsigned long long v) {
    __hip_atomic_store((unsigned long long*)p, v, __ATOMIC_RELAXED, __HIP_MEMORY_SCOPE_AGENT);
}
__device__ __forceinline__ void cstore4(void* p, unsigned v) {
    __hip_atomic_store((unsigned*)p, v, __ATOMIC_RELAXED, __HIP_MEMORY_SCOPE_AGENT);
}
__device__ __forceinline__ void fstore(unsigned* p, unsigned v) {
    __hip_atomic_store(p, v, __ATOMIC_RELAXED, __HIP_MEMORY_SCOPE_AGENT);
}
__device__ __forceinline__ unsigned long long pack4bf(float a, float b, float c, float d) {
    union { unsigned short s[4]; unsigned long long u; } x;
    union { __bf16 b; unsigned short s; } t;
    t.b = (__bf16)a; x.s[0] = t.s;
    t.b = (__bf16)b; x.s[1] = t.s;
    t.b = (__bf16)c; x.s[2] = t.s;
    t.b = (__bf16)d; x.s[3] = t.s;
    return x.u;
}
__device__ __forceinline__ unsigned pack2bf(float a, float b) {
    union { unsigned short s[2]; unsigned u; } x;
    union { __bf16 b; unsigned short s; } t;
    t.b = (__bf16)a; x.s[0] = t.s;
    t.b = (__bf16)b; x.s[1] = t.s;
    return x.u;
}

// ---- flag waits -----------------------------------------------------------
template<int NFLAGS>
__device__ __forceinline__ void flag_wait(unsigned* flags, unsigned want) {
    const int tid = (int)threadIdx.x;
    if (tid < NFLAGS) {
        while (__hip_atomic_load(&flags[tid * 16], __ATOMIC_RELAXED,
                                 __HIP_MEMORY_SCOPE_AGENT) < want)
            __builtin_amdgcn_s_sleep(1);
    }
    __syncthreads();
    if (tid == 0)
        (void)__hip_atomic_load(&flags[0], __ATOMIC_ACQUIRE, __HIP_MEMORY_SCOPE_AGENT);
    __syncthreads();
    asm volatile("" ::: "memory");
}

template<int N1, int N2>
__device__ __forceinline__ void flag_wait2(unsigned* f1, unsigned want1,
                                           unsigned* f2, unsigned want2) {
    const int tid = (int)threadIdx.x;
    if (tid < N1) {
        while (__hip_atomic_load(&f1[tid * 16], __ATOMIC_RELAXED,
                                 __HIP_MEMORY_SCOPE_AGENT) < want1)
            __builtin_amdgcn_s_sleep(1);
    } else if (tid < N1 + N2) {
        while (__hip_atomic_load(&f2[(tid - N1) * 16], __ATOMIC_RELAXED,
                                 __HIP_MEMORY_SCOPE_AGENT) < want2)
            __builtin_amdgcn_s_sleep(1);
    }
    __syncthreads();
    if (tid == 0)
        (void)__hip_atomic_load(&f1[0], __ATOMIC_ACQUIRE, __HIP_MEMORY_SCOPE_AGENT);
    __syncthreads();
    asm volatile("" ::: "memory");
}

// f32 (K x N row-major) -> bf16 transposed (N x K row-major), normal stores
__device__ __forceinline__ void transpose_cvt(const float* __restrict__ src,
                                              __bf16* __restrict__ dst,
                                              int K, int lgN) {
    const int N = 1 << lgN;
    const int total = K << lgN;
    for (int idx = (int)(blockIdx.x * blockDim.x + threadIdx.x); idx < total; idx += GSTRIDE) {
        int k = idx >> lgN;
        int n = idx & (N - 1);
        dst[(size_t)n * K + k] = (__bf16)src[idx];
    }
}

// ---- async global -> LDS, 16 B per lane (dest = uniform base + lane*16) ----
__device__ __forceinline__ void gload16(const void* g, void* l) {
    __builtin_amdgcn_global_load_lds(
        (const __attribute__((address_space(1))) unsigned int*)g,
        (__attribute__((address_space(3))) unsigned int*)l,
        16, 0, 0);
}

#define WAITV(rem)                                                            \
    do {                                                                      \
        if ((rem) >= 3)      asm volatile("s_waitcnt vmcnt(12)" ::: "memory");\
        else if ((rem) == 2) asm volatile("s_waitcnt vmcnt(8)" ::: "memory"); \
        else if ((rem) == 1) asm volatile("s_waitcnt vmcnt(4)" ::: "memory"); \
        else                 asm volatile("s_waitcnt vmcnt(0)" ::: "memory"); \
        __builtin_amdgcn_sched_barrier(0);                                    \
    } while (0)

// ---------------------------------------------------------------------------
// LDS-staged GEMM pieces (R11 engine). Tile = 64 rows x 16 cols; wave w,
// segment i covers kb = (w + i*8)*32 of A's K dim (stride ks). Per wave:
// 16KB LDS window (4 slots x 4KB). XOR swizzle: chunk j at j^((row>>1)&3).
// ---------------------------------------------------------------------------
template<int NSEG, int OFF, int N>
__device__ __forceinline__ void gemm_lds1(
    const __bf16* __restrict__ A, int ks, const bf16x8 (&pb)[N],
    f32x4 acc[4], char* __restrict__ wls)
{
    static_assert(OFF + NSEG <= N, "frags");
    const int tid  = (int)threadIdx.x;
    const int lane = tid & 63;
    const int w    = tid >> 6;
    const int l15  = lane & 15;

    auto stage = [&](int i) {
        const int kb = (w + (i << 3)) << 5;
        char* slot = wls + ((i & 3) << 12);
#pragma unroll
        for (int c = 0; c < 4; ++c) {
            const int row = (c << 4) + (lane >> 2);
            const int j = (lane & 3) ^ ((row >> 1) & 3);
            gload16(A + (size_t)row * ks + kb + (j << 3), slot + (c << 10));
        }
    };

    asm volatile("s_waitcnt lgkmcnt(0)" ::: "memory");
    __builtin_amdgcn_sched_barrier(0);
    stage(0);
    if constexpr (NSEG > 1) stage(1);
    if constexpr (NSEG > 2) stage(2);
    if constexpr (NSEG > 3) stage(3);
#pragma unroll
    for (int i = 0; i < NSEG; ++i) {
        WAITV(NSEG - 1 - i);
        const char* slot = wls + ((i & 3) << 12);
        bf16x8 pa[4];
#pragma unroll
        for (int m = 0; m < 4; ++m) {
            const int row = (m << 4) + l15;
            const int j   = (lane >> 4) ^ ((row >> 1) & 3);
            pa[m] = *(const bf16x8*)(slot + row * 64 + (j << 4));
        }
#pragma unroll
        for (int m = 0; m < 4; ++m)
            acc[m] = __builtin_amdgcn_mfma_f32_16x16x32_bf16(pa[m], pb[OFF + i], acc[m], 0, 0, 0);
        if (i + 4 < NSEG) {
            asm volatile("s_waitcnt lgkmcnt(0)" ::: "memory");
            __builtin_amdgcn_sched_barrier(0);
            stage(i + 4);
        }
    }
}

// fused phase A: 12 segments (4 X + 8 Hc); each staged segment feeds
// Z (pbZ), R (pbR), and for X segments also the H~ X-part (pbHx).
__device__ __forceinline__ void gemm_fusedA(
    const __bf16* __restrict__ Xc, const __bf16* __restrict__ Hc,
    const bf16x8 (&pbZ)[12], const bf16x8 (&pbR)[12], const bf16x8 (&pbHx)[4],
    f32x4 accZ[4], f32x4 accR[4], f32x4 accB[4], char* __restrict__ wls)
{
    const int tid  = (int)threadIdx.x;
    const int lane = tid & 63;
    const int w    = tid >> 6;
    const int l15  = lane & 15;

    auto stage = [&](int i) {
        const bool isx = (i < 4);
        const __bf16* A = isx ? Xc : Hc;
        const int ks = isx ? I_ : H_;
        const int kb = (isx ? (w + (i << 3)) : (w + ((i - 4) << 3))) << 5;
        char* slot = wls + ((i & 3) << 12);
#pragma unroll
        for (int c = 0; c < 4; ++c) {
            const int row = (c << 4) + (lane >> 2);
            const int j = (lane & 3) ^ ((row >> 1) & 3);
            gload16(A + (size_t)row * ks + kb + (j << 3), slot + (c << 10));
        }
    };

    asm volatile("s_waitcnt lgkmcnt(0)" ::: "memory");
    __builtin_amdgcn_sched_barrier(0);
    stage(0); stage(1); stage(2); stage(3);
#pragma unroll
    for (int i = 0; i < 12; ++i) {
        WAITV(11 - i);
        const char* slot = wls + ((i & 3) << 12);
        bf16x8 pa[4];
#pragma unroll
        for (int m = 0; m < 4; ++m) {
            const int row = (m << 4) + l15;
            const int j   = (lane >> 4) ^ ((row >> 1) & 3);
            pa[m] = *(const bf16x8*)(slot + row * 64 + (j << 4));
        }
#pragma unroll
        for (int m = 0; m < 4; ++m)
            accZ[m] = __builtin_amdgcn_mfma_f32_16x16x32_bf16(pa[m], pbZ[i], accZ[m], 0, 0, 0);
#pragma unroll
        for (int m = 0; m < 4; ++m)
            accR[m] = __builtin_amdgcn_mfma_f32_16x16x32_bf16(pa[m], pbR[i], accR[m], 0, 0, 0);
        if (i < 4) {
#pragma unroll
            for (int m = 0; m < 4; ++m)
                accB[m] = __builtin_amdgcn_mfma_f32_16x16x32_bf16(pa[m], pbHx[i], accB[m], 0, 0, 0);
        }
        if (i + 4 < 12) {
            asm volatile("s_waitcnt lgkmcnt(0)" ::: "memory");
            __builtin_amdgcn_sched_barrier(0);
            stage(i + 4);
        }
    }
}

// cross-wave reduction through LDS (64x16 tile, pitch 20)
__device__ __forceinline__ void gemm_reduce(f32x4 acc[4], float* __restrict__ red,
                                            float out2[2]) {
    constexpr int RP = 20;
    const int tid  = (int)threadIdx.x;
    const int lane = tid & 63;
    const int w    = tid >> 6;
    const int l15  = lane & 15;
    const int q4   = (lane >> 4) << 2;

    if (w >= 4) {
        float* rw = red + (size_t)(w - 4) * (64 * RP);
#pragma unroll
        for (int m = 0; m < 4; ++m)
#pragma unroll
            for (int r = 0; r < 4; ++r)
                rw[((m << 4) + q4 + r) * RP + l15] = acc[m][r];
    }
    __syncthreads();
    if (w < 4) {
        float* rw = red + (size_t)w * (64 * RP);
#pragma unroll
        for (int m = 0; m < 4; ++m)
#pragma unroll
            for (int r = 0; r < 4; ++r)
                rw[((m << 4) + q4 + r) * RP + l15] += acc[m][r];
    }
    __syncthreads();
    {
        const int a = (tid >> 3) * RP + ((tid & 7) << 1);
        f32x2 s0 = *(const f32x2*)(red + a);
        f32x2 s1 = *(const f32x2*)(red + 64 * RP + a);
        f32x2 s2 = *(const f32x2*)(red + 2 * 64 * RP + a);
        f32x2 s3 = *(const f32x2*)(red + 3 * 64 * RP + a);
        f32x2 s = s0 + s1 + s2 + s3;
        out2[0] = s[0]; out2[1] = s[1];
    }
}

__global__ __launch_bounds__(NTHREADS, 2)
__attribute__((amdgpu_waves_per_eu(2, 2)))
void gru_persistent(
    const float* __restrict__ inputs, const float* __restrict__ state,
    const float* __restrict__ Wxz, const float* __restrict__ Whz, const float* __restrict__ bz,
    const float* __restrict__ Wxr, const float* __restrict__ Whr, const float* __restrict__ br,
    const float* __restrict__ Wxh, const float* __restrict__ Whh, const float* __restrict__ bh,
    const float* __restrict__ Whq, const float* __restrict__ bhq,
    float* __restrict__ out, char* __restrict__ ws) {

    unsigned* slots = (unsigned*)(ws + OFF_SLOT);   // prologue barrier
    unsigned* hnf   = (unsigned*)(ws + OFF_HNF);    // 128
    unsigned* rhf   = (unsigned*)(ws + OFF_RHF);    // 128
    unsigned* xf    = (unsigned*)(ws + OFF_XF);     // 64
    unsigned* yf    = (unsigned*)(ws + OFF_YF);     // 64
    __bf16* WxzT = (__bf16*)(ws + OFF_WXZT);
    __bf16* WxrT = (__bf16*)(ws + OFF_WXRT);
    __bf16* WxhT = (__bf16*)(ws + OFF_WXHT);
    __bf16* WhzT = (__bf16*)(ws + OFF_WHZT);
    __bf16* WhrT = (__bf16*)(ws + OFF_WHRT);
    __bf16* WhhT = (__bf16*)(ws + OFF_WHHT);
    __bf16* WhqT = (__bf16*)(ws + OFF_WHQT);
    __bf16* Xbf  = (__bf16*)(ws + OFF_XBF);   // 2 x (64 x 1024)
    __bf16* Hbf  = (__bf16*)(ws + OFF_HBF);   // 2 x (64 x 2048)
    __bf16* RHbf = (__bf16*)(ws + OFF_RHBF);  // 64 x 2048

    extern __shared__ char smem[];            // 128KB staging + 20KB reduce
    char* wls  = smem + ((threadIdx.x >> 6) << 14);
    float* red = (float*)(smem + 128 * 1024);

    const int b   = (int)blockIdx.x;
    const int tid = (int)threadIdx.x;
    const int gr  = tid >> 3;                 // output row this thread owns
    const int gc  = (tid & 7) << 1;           // output col (2 consecutive)

    // ---------------- prologue ---------------------------------------------
    transpose_cvt(Wxz, WxzT, I_, 11);
    transpose_cvt(Wxr, WxrT, I_, 11);
    transpose_cvt(Wxh, WxhT, I_, 11);
    transpose_cvt(Whz, WhzT, H_, 11);
    transpose_cvt(Whr, WhrT, H_, 11);
    transpose_cvt(Whh, WhhT, H_, 11);
    transpose_cvt(Whq, WhqT, H_, 10);
    {
        int q = b * NTHREADS + tid;           // quad index
        if (q < B_ * I_ / 4) {
            f32x4 v = *(const f32x4*)(inputs + (size_t)q * 4);
            cstore8(Xbf + (size_t)q * 4, pack4bf(v[0], v[1], v[2], v[3]));
        }
        if (q < B_ * H_ / 4) {
            f32x4 v = *(const f32x4*)(state + (size_t)q * 4);
            cstore8(Hbf + (size_t)q * 4, pack4bf(v[0], v[1], v[2], v[3]));
        }
    }
    __syncthreads();
    __threadfence();   // flush write-back transpose stores
    if (tid == 0) fstore(&slots[b * 16], 1u);
    flag_wait<256>(slots, 1u);

    const int lane = tid & 63;
    const int w    = tid >> 6;
    const int l15  = lane & 15;
    const int q8   = (lane >> 4) << 3;

    if (b < 128) {
        // ======== FUSED GATE BLOCKS: Z, R, H~, H_new for 16 cols ===========
        const int c16 = b << 4;
        bf16x8 pbZ[12];   // Wxz | Whz
        bf16x8 pbR[12];   // Wxr | Whr
        bf16x8 pbHx[4];   // Wxh
        bf16x8 pbHh[8];   // Whh
#pragma unroll
        for (int i = 0; i < 4; ++i)
            pbZ[i] = *(const bf16x8*)(WxzT + (size_t)(c16 + l15) * I_ + ((w + (i << 3)) << 5) + q8);
#pragma unroll
        for (int i = 0; i < 8; ++i)
            pbZ[4 + i] = *(const bf16x8*)(WhzT + (size_t)(c16 + l15) * H_ + ((w + (i << 3)) << 5) + q8);
#pragma unroll
        for (int i = 0; i < 4; ++i)
            pbR[i] = *(const bf16x8*)(WxrT + (size_t)(c16 + l15) * I_ + ((w + (i << 3)) << 5) + q8);
#pragma unroll
        for (int i = 0; i < 8; ++i)
            pbR[4 + i] = *(const bf16x8*)(WhrT + (size_t)(c16 + l15) * H_ + ((w + (i << 3)) << 5) + q8);
#pragma unroll
        for (int i = 0; i < 4; ++i)
            pbHx[i] = *(const bf16x8*)(WxhT + (size_t)(c16 + l15) * I_ + ((w + (i << 3)) << 5) + q8);
#pragma unroll
        for (int i = 0; i < 8; ++i)
            pbHh[i] = *(const bf16x8*)(WhhT + (size_t)(c16 + l15) * H_ + ((w + (i << 3)) << 5) + q8);

        const float bz0 = bz[c16 + gc], bz1 = bz[c16 + gc + 1];
        const float br0 = br[c16 + gc], br1 = br[c16 + gc + 1];
        const float bh0 = bh[c16 + gc], bh1 = bh[c16 + gc + 1];
        float hreg[2];
        {
            f32x2 v = *(const f32x2*)(state + (size_t)gr * H_ + c16 + gc);
            hreg[0] = v[0]; hreg[1] = v[1];
        }

        for (int t = 0; t < T_; ++t) {
            const int cur = t & 1, nxt = cur ^ 1;
            const __bf16* Xc = Xbf + (size_t)cur * B_ * I_;
            const __bf16* Hc = Hbf + (size_t)cur * B_ * H_;
            float o2[2];

            // ---- wait H_t (hnf>=t) and X_t (xf>=t) ----
            flag_wait2<128, 64>(hnf, (unsigned)t, xf, (unsigned)t);

            // ---- fused phase A: one pass over X+Hc feeds Z, R, H~x ----
            f32x4 accZ[4], accR[4], accB[4];
#pragma unroll
            for (int m = 0; m < 4; ++m) {
                accZ[m] = f32x4{0.f, 0.f, 0.f, 0.f};
                accR[m] = f32x4{0.f, 0.f, 0.f, 0.f};
                accB[m] = f32x4{0.f, 0.f, 0.f, 0.f};
            }
            gemm_fusedA(Xc, Hc, pbZ, pbR, pbHx, accZ, accR, accB, wls);
            gemm_reduce(accZ, red, o2);
            const float z0 = fsigmoid(o2[0] + bz0);
            const float z1 = fsigmoid(o2[1] + bz1);
            __syncthreads();   // red reuse guard
            gemm_reduce(accR, red, o2);
            bf16x2 h2 = *(const bf16x2*)(Hc + (size_t)gr * H_ + c16 + gc);
            const float rh0 = fsigmoid(o2[0] + br0) * (float)h2[0];
            const float rh1 = fsigmoid(o2[1] + br1) * (float)h2[1];
            cstore4(RHbf + (size_t)gr * H_ + c16 + gc, pack2bf(rh0, rh1));
            __syncthreads();   // drain RH stores (vmcnt(0) before barrier)
            if (tid == 0) fstore(&rhf[b * 16], (unsigned)(t + 1));

            // ---- wait full RH (rhf>=t+1) and Y readers of H-slot (yf>=t) ----
            flag_wait2<128, 64>(rhf, (unsigned)(t + 1), yf, (unsigned)t);

            // ---- phase B: H~ RH-part, H_new ----
            gemm_lds1<8, 0>(RHbf, H_, pbHh, accB, wls);
            gemm_reduce(accB, red, o2);
            const float ht0 = ftanh(o2[0] + bh0);
            const float ht1 = ftanh(o2[1] + bh1);
            const float hn0 = z0 * hreg[0] + (1.0f - z0) * ht0;
            const float hn1 = z1 * hreg[1] + (1.0f - z1) * ht1;
            hreg[0] = hn0; hreg[1] = hn1;
            cstore4(Hbf + (size_t)nxt * B_ * H_ + (size_t)gr * H_ + c16 + gc,
                    pack2bf(hn0, hn1));
            if (t == T_ - 1) {
                f32x2 v; v[0] = hn0; v[1] = hn1;
                *(f32x2*)(out + (size_t)T_ * B_ * I_ + (size_t)gr * H_ + c16 + gc) = v;
            }
            __syncthreads();   // drain H stores
            if (tid == 0) fstore(&hnf[b * 16], (unsigned)(t + 1));
        }
    } else if (b < 192) {
        // ======== Y BLOCKS: Y_{t-1} = H_t @ Whq for 16 cols ================
        const int yc = (b - 128) << 4;
        bf16x8 pbY[8];
#pragma unroll
        for (int i = 0; i < 8; ++i)
            pbY[i] = *(const bf16x8*)(WhqT + (size_t)(yc + l15) * H_ + ((w + (i << 3)) << 5) + q8);
        const float bq0 = bhq[yc + gc], bq1 = bhq[yc + gc + 1];

        for (int t = 0; t < T_; ++t) {
            const __bf16* Hc = Hbf + (size_t)(t & 1) * B_ * H_;
            flag_wait<128>(hnf, (unsigned)t);
            if (t > 0) {
                f32x4 accY[4];
#pragma unroll
                for (int m = 0; m < 4; ++m) accY[m] = f32x4{0.f, 0.f, 0.f, 0.f};
                float o2[2];
                gemm_lds1<8, 0>(Hc, H_, pbY, accY, wls);
                gemm_reduce(accY, red, o2);
                f32x2 v;
                v[0] = o2[0] + bq0;
                v[1] = o2[1] + bq1;
                *(f32x2*)(out + ((size_t)(t - 1) * B_ + gr) * I_ + yc + gc) = v;
            }
            if (tid == 0) fstore(&yf[(b - 128) * 16], (unsigned)(t + 1));
        }

        // epilogue: Y_{T-1} (H_T lives in slot (T_ & 1) == 0)
        {
            flag_wait<128>(hnf, (unsigned)T_);
            f32x4 accY[4];
#pragma unroll
            for (int m = 0; m < 4; ++m) accY[m] = f32x4{0.f, 0.f, 0.f, 0.f};
            float o2[2];
            gemm_lds1<8, 0>(Hbf, H_, pbY, accY, wls);
            gemm_reduce(accY, red, o2);
            f32x2 v;
            v[0] = o2[0] + bq0;
            v[1] = o2[1] + bq1;
            *(f32x2*)(out + ((size_t)(T_ - 1) * B_ + gr) * I_ + yc + gc) = v;
        }
    } else {
        // ======== CONV BLOCKS: X_{t+1} f32 -> bf16 =========================
        for (int t = 0; t + 1 < T_; ++t) {
            const int nxt = (t & 1) ^ 1;
            // WAR: X slot nxt last read at fused phase A of step t-1
            flag_wait<128>(rhf, (unsigned)t);
            if (tid < 256) {
                const int idx = (((b - 192) << 8) + tid) << 2;
                f32x4 v = *(const f32x4*)(inputs + (size_t)(t + 1) * B_ * I_ + idx);
                cstore8(Xbf + (size_t)nxt * B_ * I_ + idx,
                        pack4bf(v[0], v[1], v[2], v[3]));
            }
            __syncthreads();   // drain X stores
            if (tid == 0) fstore(&xf[(b - 192) * 16], (unsigned)(t + 1));
        }
    }
}

extern "C" void kernel_launch(void* const* d_in, const int* in_sizes, int n_in,
                              void* d_out, int out_size, void* d_ws, size_t ws_size,
                              hipStream_t stream) {
    if (ws_size < WS_NEEDED) return;  // ~41.5 MB scratch required

    const float* inputs = (const float*)d_in[0];
    const float* state  = (const float*)d_in[1];
    const float* Wxz    = (const float*)d_in[2];
    const float* Whz    = (const float*)d_in[3];
    const float* bz     = (const float*)d_in[4];
    const float* Wxr    = (const float*)d_in[5];
    const float* Whr    = (const float*)d_in[6];
    const float* br     = (const float*)d_in[7];
    const float* Wxh    = (const float*)d_in[8];
    const float* Whh    = (const float*)d_in[9];
    const float* bh     = (const float*)d_in[10];
    const float* Whq    = (const float*)d_in[11];
    const float* bhq    = (const float*)d_in[12];

    static bool smem_set = false;
    if (!smem_set) {
        (void)hipFuncSetAttribute((const void*)gru_persistent,
                                  hipFuncAttributeMaxDynamicSharedMemorySize,
                                  (int)SMEM_BYTES);
        smem_set = true;
    }

    hipMemsetAsync(d_ws, 0, 40960, stream);  // slots + hnf + rhf + xf + yf
    gru_persistent<<<NB, NTHREADS, SMEM_BYTES, stream>>>(
        inputs, state, Wxz, Whz, bz, Wxr, Whr, br, Wxh, Whh, bh, Whq, bhq,
        (float*)d_out, (char*)d_ws);
}

// Round 11
// 8361.868 us; speedup vs baseline: 1.5318x; 1.5318x over previous
//
#include <hip/hip_runtime.h>
#include <cstdint>
#include <cstddef>

// ---------------------------------------------------------------------------
// GRU persistent kernel, round 13: R11 engine + coherent DMA (acquire-free).
//   - R12's fusion regressed (critical-path-bound, not BW-bound) -> reverted
//     to R11's parallel block-class partition (best: 9.01 ms).
//   - global_load_lds now carries aux=17 (sc0|sc1): DMA reads bypass L1/L2
//     and read the LLC directly -> always-fresh activations WITHOUT any
//     buffer_inv. Steady-state flag waits drop the ACQUIRE (poll + one
//     __syncthreads only). Prologue barrier keeps full acquire semantics
//     (weights are pinned via normal loads once).
//   - the one remaining normal cross-block load (h2 from Hc) is now a
//     relaxed agent atomic load (4 B, coherent).
//   - everything else identical to R11 (flag dataflow, DMA staging windows,
//     counted vmcnt, XOR swizzle, pinned weights, PIPE=4).
// ---------------------------------------------------------------------------

#define T_ 512
#define B_ 64
#define I_ 1024
#define H_ 2048
#define NB 256
#define NTHREADS 512
#define GSTRIDE (NB * NTHREADS)

typedef __attribute__((ext_vector_type(8))) __bf16 bf16x8;
typedef __attribute__((ext_vector_type(2))) __bf16 bf16x2;
typedef __attribute__((ext_vector_type(4))) float f32x4;
typedef __attribute__((ext_vector_type(2))) float f32x2;

static constexpr unsigned SMEM_BYTES = 128 * 1024 + 20 * 1024;  // staging + reduce

// ---- workspace layout (bytes) ----
static constexpr size_t OFF_SLOT = 0;
static constexpr size_t OFF_HNF  = 16384;
static constexpr size_t OFF_RHF  = 24576;
static constexpr size_t OFF_XF   = 32768;
static constexpr size_t OFF_WXZT = 36864;
static constexpr size_t SZ_WXT   = (size_t)H_ * I_ * 2;    // 4 MiB
static constexpr size_t SZ_WHT   = (size_t)H_ * H_ * 2;    // 8 MiB
static constexpr size_t OFF_WXRT = OFF_WXZT + SZ_WXT;
static constexpr size_t OFF_WXHT = OFF_WXRT + SZ_WXT;
static constexpr size_t OFF_WHZT = OFF_WXHT + SZ_WXT;
static constexpr size_t OFF_WHRT = OFF_WHZT + SZ_WHT;
static constexpr size_t OFF_WHHT = OFF_WHRT + SZ_WHT;
static constexpr size_t OFF_WHQT = OFF_WHHT + SZ_WHT;      // N=1024,K=2048
static constexpr size_t OFF_XBF  = OFF_WHQT + SZ_WXT;
static constexpr size_t OFF_HBF  = OFF_XBF + (size_t)2 * B_ * I_ * 2;
static constexpr size_t OFF_RHBF = OFF_HBF + (size_t)2 * B_ * H_ * 2;
static constexpr size_t WS_NEEDED = OFF_RHBF + (size_t)B_ * H_ * 2;

__device__ __forceinline__ float fsigmoid(float x) { return 1.0f / (1.0f + __expf(-x)); }
__device__ __forceinline__ float ftanh(float x)    { return 2.0f / (1.0f + __expf(-2.0f * x)) - 1.0f; }

// ---- coherent (sc1 write-through) stores for cross-block data ----
__device__ __forceinline__ void cstore8(void* p, unsigned long long v) {
    __hip_atomic_store((unsigned long long*)p, v, __ATOMIC_RELAXED, __HIP_MEMORY_SCOPE_AGENT);
}
__device__ __forceinline__ void cstore4(void* p, unsigned v) {
    __hip_atomic_store((unsigned*)p, v, __ATOMIC_RELAXED, __HIP_MEMORY_SCOPE_AGENT);
}
__device__ __forceinline__ void fstore(unsigned* p, unsigned v) {
    __hip_atomic_store(p, v, __ATOMIC_RELAXED, __HIP_MEMORY_SCOPE_AGENT);
}
__device__ __forceinline__ unsigned long long pack4bf(float a, float b, float c, float d) {
    union { unsigned short s[4]; unsigned long long u; } x;
    union { __bf16 b; unsigned short s; } t;
    t.b = (__bf16)a; x.s[0] = t.s;
    t.b = (__bf16)b; x.s[1] = t.s;
    t.b = (__bf16)c; x.s[2] = t.s;
    t.b = (__bf16)d; x.s[3] = t.s;
    return x.u;
}
__device__ __forceinline__ unsigned pack2bf(float a, float b) {
    union { unsigned short s[2]; unsigned u; } x;
    union { __bf16 b; unsigned short s; } t;
    t.b = (__bf16)a; x.s[0] = t.s;
    t.b = (__bf16)b; x.s[1] = t.s;
    return x.u;
}
// coherent 2x bf16 load (relaxed agent atomic, 4 B aligned)
__device__ __forceinline__ void load_h2(const __bf16* p, float& h0, float& h1) {
    unsigned u = __hip_atomic_load((const unsigned*)p, __ATOMIC_RELAXED,
                                   __HIP_MEMORY_SCOPE_AGENT);
    union { unsigned short s; __bf16 b; } t0, t1;
    t0.s = (unsigned short)(u & 0xffffu);
    t1.s = (unsigned short)(u >> 16);
    h0 = (float)t0.b; h1 = (float)t1.b;
}

// ---- flag waits -----------------------------------------------------------
// prologue version: WITH acquire (weights consumed via normal loads after it)
template<int NFLAGS>
__device__ __forceinline__ void flag_wait_acq(unsigned* flags, unsigned want) {
    const int tid = (int)threadIdx.x;
    if (tid < NFLAGS) {
        while (__hip_atomic_load(&flags[tid * 16], __ATOMIC_RELAXED,
                                 __HIP_MEMORY_SCOPE_AGENT) < want)
            __builtin_amdgcn_s_sleep(1);
    }
    __syncthreads();
    if (tid == 0)
        (void)__hip_atomic_load(&flags[0], __ATOMIC_ACQUIRE, __HIP_MEMORY_SCOPE_AGENT);
    __syncthreads();
    asm volatile("" ::: "memory");
}

// steady-state version: NO acquire (all consumption is coherent sc0|sc1 DMA
// or relaxed atomic loads; no cached normal loads of cross-block data)
template<int NFLAGS>
__device__ __forceinline__ void flag_wait_na(unsigned* flags, unsigned want) {
    const int tid = (int)threadIdx.x;
    if (tid < NFLAGS) {
        while (__hip_atomic_load(&flags[tid * 16], __ATOMIC_RELAXED,
                                 __HIP_MEMORY_SCOPE_AGENT) < want)
            __builtin_amdgcn_s_sleep(1);
    }
    __syncthreads();
    asm volatile("" ::: "memory");
}

// f32 (K x N row-major) -> bf16 transposed (N x K row-major), normal stores
__device__ __forceinline__ void transpose_cvt(const float* __restrict__ src,
                                              __bf16* __restrict__ dst,
                                              int K, int lgN) {
    const int N = 1 << lgN;
    const int total = K << lgN;
    for (int idx = (int)(blockIdx.x * blockDim.x + threadIdx.x); idx < total; idx += GSTRIDE) {
        int k = idx >> lgN;
        int n = idx & (N - 1);
        dst[(size_t)n * K + k] = (__bf16)src[idx];
    }
}

// ---- async global -> LDS, 16 B/lane, COHERENT (aux=17: sc0|sc1 -> bypass
// L1/L2, read LLC) -----------------------------------------------------------
__device__ __forceinline__ void gload16(const void* g, void* l) {
    __builtin_amdgcn_global_load_lds(
        (const __attribute__((address_space(1))) unsigned int*)g,
        (__attribute__((address_space(3))) unsigned int*)l,
        16, 0, 17);
}

// ---------------------------------------------------------------------------
// LDS-staged GEMM. Tile = 64 rows x 16 cols; wave w, segment i covers
// kb = (w + i*8)*32 of A's K dim (stride ks). Per wave: 16KB LDS window,
// 4 slots x 4KB. Counted vmcnt; XOR swizzle chunk j at j^((row>>1)&3).
// ---------------------------------------------------------------------------
#define STAGE_SEG(i)                                                          \
    do {                                                                      \
        const int kb_ = (w + ((i) << 3)) << 5;                                \
        char* slot_ = wls + (((i) & 3) << 12);                                \
        _Pragma("unroll")                                                     \
        for (int c_ = 0; c_ < 4; ++c_) {                                      \
            const int row_ = (c_ << 4) + (lane >> 2);                         \
            const int jl_ = (lane & 3) ^ ((row_ >> 1) & 3);                   \
            gload16(A + (size_t)row_ * ks + kb_ + (jl_ << 3),                 \
                    slot_ + (c_ << 10));                                      \
        }                                                                     \
    } while (0)

#define WAITV(rem)                                                            \
    do {                                                                      \
        if ((rem) >= 3)      asm volatile("s_waitcnt vmcnt(12)" ::: "memory");\
        else if ((rem) == 2) asm volatile("s_waitcnt vmcnt(8)" ::: "memory"); \
        else if ((rem) == 1) asm volatile("s_waitcnt vmcnt(4)" ::: "memory"); \
        else                 asm volatile("s_waitcnt vmcnt(0)" ::: "memory"); \
        __builtin_amdgcn_sched_barrier(0);                                    \
    } while (0)

template<int NSEG, int OFF, int N>
__device__ __forceinline__ void gemm_lds1(
    const __bf16* __restrict__ A, int ks, const bf16x8 (&pb)[N],
    f32x4 acc[4], char* __restrict__ wls)
{
    static_assert(OFF + NSEG <= N, "frags");
    const int tid  = (int)threadIdx.x;
    const int lane = tid & 63;
    const int w    = tid >> 6;
    const int l15  = lane & 15;

    // guard: prior ds_reads of these slots must retire before DMA overwrites
    asm volatile("s_waitcnt lgkmcnt(0)" ::: "memory");
    __builtin_amdgcn_sched_barrier(0);
    STAGE_SEG(0);
    if constexpr (NSEG > 1) STAGE_SEG(1);
    if constexpr (NSEG > 2) STAGE_SEG(2);
    if constexpr (NSEG > 3) STAGE_SEG(3);
#pragma unroll
    for (int i = 0; i < NSEG; ++i) {
        WAITV(NSEG - 1 - i);
        const char* slot = wls + ((i & 3) << 12);
        bf16x8 pa[4];
#pragma unroll
        for (int m = 0; m < 4; ++m) {
            const int row = (m << 4) + l15;
            const int j   = (lane >> 4) ^ ((row >> 1) & 3);
            pa[m] = *(const bf16x8*)(slot + row * 64 + (j << 4));
        }
#pragma unroll
        for (int m = 0; m < 4; ++m)
            acc[m] = __builtin_amdgcn_mfma_f32_16x16x32_bf16(pa[m], pb[OFF + i], acc[m], 0, 0, 0);
        if (i + 4 < NSEG) {
            asm volatile("s_waitcnt lgkmcnt(0)" ::: "memory");
            __builtin_amdgcn_sched_barrier(0);
            STAGE_SEG(i + 4);
        }
    }
}

// 4-segment X pass feeding TWO accumulator sets (one panel read, 2 gates)
template<int N1, int N2>
__device__ __forceinline__ void gemm_lds2(
    const __bf16* __restrict__ A, int ks,
    const bf16x8 (&pb1)[N1], const bf16x8 (&pb2)[N2],
    f32x4 a1[4], f32x4 a2[4], char* __restrict__ wls)
{
    const int tid  = (int)threadIdx.x;
    const int lane = tid & 63;
    const int w    = tid >> 6;
    const int l15  = lane & 15;

    asm volatile("s_waitcnt lgkmcnt(0)" ::: "memory");
    __builtin_amdgcn_sched_barrier(0);
    STAGE_SEG(0); STAGE_SEG(1); STAGE_SEG(2); STAGE_SEG(3);
#pragma unroll
    for (int i = 0; i < 4; ++i) {
        WAITV(3 - i);
        const char* slot = wls + ((i & 3) << 12);
        bf16x8 pa[4];
#pragma unroll
        for (int m = 0; m < 4; ++m) {
            const int row = (m << 4) + l15;
            const int j   = (lane >> 4) ^ ((row >> 1) & 3);
            pa[m] = *(const bf16x8*)(slot + row * 64 + (j << 4));
        }
#pragma unroll
        for (int m = 0; m < 4; ++m) {
            a1[m] = __builtin_amdgcn_mfma_f32_16x16x32_bf16(pa[m], pb1[i], a1[m], 0, 0, 0);
            a2[m] = __builtin_amdgcn_mfma_f32_16x16x32_bf16(pa[m], pb2[i], a2[m], 0, 0, 0);
        }
    }
}

// cross-wave reduction through LDS (64x16 tile, pitch 20)
__device__ __forceinline__ void gemm_reduce(f32x4 acc[4], float* __restrict__ red,
                                            float out2[2]) {
    constexpr int RP = 20;
    const int tid  = (int)threadIdx.x;
    const int lane = tid & 63;
    const int w    = tid >> 6;
    const int l15  = lane & 15;
    const int q4   = (lane >> 4) << 2;

    if (w >= 4) {
        float* rw = red + (size_t)(w - 4) * (64 * RP);
#pragma unroll
        for (int m = 0; m < 4; ++m)
#pragma unroll
            for (int r = 0; r < 4; ++r)
                rw[((m << 4) + q4 + r) * RP + l15] = acc[m][r];
    }
    __syncthreads();
    if (w < 4) {
        float* rw = red + (size_t)w * (64 * RP);
#pragma unroll
        for (int m = 0; m < 4; ++m)
#pragma unroll
            for (int r = 0; r < 4; ++r)
                rw[((m << 4) + q4 + r) * RP + l15] += acc[m][r];
    }
    __syncthreads();
    {
        const int a = (tid >> 3) * RP + ((tid & 7) << 1);
        f32x2 s0 = *(const f32x2*)(red + a);
        f32x2 s1 = *(const f32x2*)(red + 64 * RP + a);
        f32x2 s2 = *(const f32x2*)(red + 2 * 64 * RP + a);
        f32x2 s3 = *(const f32x2*)(red + 3 * 64 * RP + a);
        f32x2 s = s0 + s1 + s2 + s3;
        out2[0] = s[0]; out2[1] = s[1];
    }
}

__global__ __launch_bounds__(NTHREADS, 2)
__attribute__((amdgpu_waves_per_eu(2, 2)))
void gru_persistent(
    const float* __restrict__ inputs, const float* __restrict__ state,
    const float* __restrict__ Wxz, const float* __restrict__ Whz, const float* __restrict__ bz,
    const float* __restrict__ Wxr, const float* __restrict__ Whr, const float* __restrict__ br,
    const float* __restrict__ Wxh, const float* __restrict__ Whh, const float* __restrict__ bh,
    const float* __restrict__ Whq, const float* __restrict__ bhq,
    float* __restrict__ out, char* __restrict__ ws) {

    unsigned* slots = (unsigned*)(ws + OFF_SLOT);   // 256 x 64B
    unsigned* hnf   = (unsigned*)(ws + OFF_HNF);    // 128 x 64B
    unsigned* rhf   = (unsigned*)(ws + OFF_RHF);    // 128 x 64B
    unsigned* xf    = (unsigned*)(ws + OFF_XF);     // 64 x 64B
    __bf16* WxzT = (__bf16*)(ws + OFF_WXZT);
    __bf16* WxrT = (__bf16*)(ws + OFF_WXRT);
    __bf16* WxhT = (__bf16*)(ws + OFF_WXHT);
    __bf16* WhzT = (__bf16*)(ws + OFF_WHZT);
    __bf16* WhrT = (__bf16*)(ws + OFF_WHRT);
    __bf16* WhhT = (__bf16*)(ws + OFF_WHHT);
    __bf16* WhqT = (__bf16*)(ws + OFF_WHQT);
    __bf16* Xbf  = (__bf16*)(ws + OFF_XBF);   // 2 x (64 x 1024)
    __bf16* Hbf  = (__bf16*)(ws + OFF_HBF);   // 2 x (64 x 2048)
    __bf16* RHbf = (__bf16*)(ws + OFF_RHBF);  // 64 x 2048

    extern __shared__ char smem[];            // 128KB staging + 20KB reduce
    char* wls  = smem + ((threadIdx.x >> 6) << 14);
    float* red = (float*)(smem + 128 * 1024);

    const int b   = (int)blockIdx.x;
    const int tid = (int)threadIdx.x;
    const int c16 = (b & 127) << 4;           // col base (Z cols b<128, R cols else)
    const int gr  = tid >> 3;                 // output row this thread owns
    const int gc  = (tid & 7) << 1;           // output col (2 consecutive)

    // ---------------- prologue ---------------------------------------------
    transpose_cvt(Wxz, WxzT, I_, 11);
    transpose_cvt(Wxr, WxrT, I_, 11);
    transpose_cvt(Wxh, WxhT, I_, 11);
    transpose_cvt(Whz, WhzT, H_, 11);
    transpose_cvt(Whr, WhrT, H_, 11);
    transpose_cvt(Whh, WhhT, H_, 11);
    transpose_cvt(Whq, WhqT, H_, 10);
    {
        int q = b * NTHREADS + tid;           // quad index
        if (q < B_ * I_ / 4) {
            f32x4 v = *(const f32x4*)(inputs + (size_t)q * 4);
            cstore8(Xbf + (size_t)q * 4, pack4bf(v[0], v[1], v[2], v[3]));
        }
        if (q < B_ * H_ / 4) {
            f32x4 v = *(const f32x4*)(state + (size_t)q * 4);
            cstore8(Hbf + (size_t)q * 4, pack4bf(v[0], v[1], v[2], v[3]));
        }
    }
    __syncthreads();
    __threadfence();   // flush write-back transpose stores
    if (tid == 0) fstore(&slots[b * 16], 1u);
    flag_wait_acq<256>(slots, 1u);

    const int lane = tid & 63;
    const int w    = tid >> 6;
    const int l15  = lane & 15;
    const int q8   = (lane >> 4) << 3;

    if (b < 128) {
        // ======== GATE (Z) BLOCKS: Z, H~, H_new for 16 cols ================
        bf16x8 pbA[12];   // Wxz | Whz
        bf16x8 pbB[12];   // Wxh | Whh
#pragma unroll
        for (int i = 0; i < 4; ++i)
            pbA[i] = *(const bf16x8*)(WxzT + (size_t)(c16 + l15) * I_ + ((w + (i << 3)) << 5) + q8);
#pragma unroll
        for (int i = 0; i < 8; ++i)
            pbA[4 + i] = *(const bf16x8*)(WhzT + (size_t)(c16 + l15) * H_ + ((w + (i << 3)) << 5) + q8);
#pragma unroll
        for (int i = 0; i < 4; ++i)
            pbB[i] = *(const bf16x8*)(WxhT + (size_t)(c16 + l15) * I_ + ((w + (i << 3)) << 5) + q8);
#pragma unroll
        for (int i = 0; i < 8; ++i)
            pbB[4 + i] = *(const bf16x8*)(WhhT + (size_t)(c16 + l15) * H_ + ((w + (i << 3)) << 5) + q8);

        const float bz0 = bz[c16 + gc], bz1 = bz[c16 + gc + 1];
        const float bh0 = bh[c16 + gc], bh1 = bh[c16 + gc + 1];
        float hreg[2];
        {
            f32x2 v = *(const f32x2*)(state + (size_t)gr * H_ + c16 + gc);
            hreg[0] = v[0]; hreg[1] = v[1];
        }

        // t=0 fused X prefetch (X_0 published at prologue)
        f32x4 accA[4], accB[4];
#pragma unroll
        for (int m = 0; m < 4; ++m) {
            accA[m] = f32x4{0.f, 0.f, 0.f, 0.f};
            accB[m] = f32x4{0.f, 0.f, 0.f, 0.f};
        }
        gemm_lds2(Xbf, I_, pbA, pbB, accA, accB, wls);

        for (int t = 0; t < T_; ++t) {
            const int cur = t & 1, nxt = cur ^ 1;
            const __bf16* Hc = Hbf + (size_t)cur * B_ * H_;
            float o2[2];

            // ---- phase A: finish Z (H_t ready when all hnf >= t) ----
            flag_wait_na<128>(hnf, (unsigned)t);
            gemm_lds1<8, 4>(Hc, H_, pbA, accA, wls);
            gemm_reduce(accA, red, o2);
            const float z0 = fsigmoid(o2[0] + bz0);
            const float z1 = fsigmoid(o2[1] + bz1);

            // ---- phase B (rhf>=t+1 implies all blocks finished step t-1) ----
            flag_wait_na<128>(rhf, (unsigned)(t + 1));
            gemm_lds1<8, 4>(RHbf, H_, pbB, accB, wls);
            gemm_reduce(accB, red, o2);
            const float ht0 = ftanh(o2[0] + bh0);
            const float ht1 = ftanh(o2[1] + bh1);
            const float hn0 = z0 * hreg[0] + (1.0f - z0) * ht0;
            const float hn1 = z1 * hreg[1] + (1.0f - z1) * ht1;
            hreg[0] = hn0; hreg[1] = hn1;
            cstore4(Hbf + (size_t)nxt * B_ * H_ + (size_t)gr * H_ + c16 + gc,
                    pack2bf(hn0, hn1));
            if (t == T_ - 1) {
                f32x2 v; v[0] = hn0; v[1] = hn1;
                *(f32x2*)(out + (size_t)T_ * B_ * I_ + (size_t)gr * H_ + c16 + gc) = v;
            }
            __syncthreads();   // drain H stores
            if (tid == 0) {
                fstore(&hnf[b * 16], (unsigned)(t + 1));
                fstore(&slots[b * 16], (unsigned)(t + 2));
            }

            // ---- window: fused X prefetch for step t+1 ----
#pragma unroll
            for (int m = 0; m < 4; ++m) {
                accA[m] = f32x4{0.f, 0.f, 0.f, 0.f};
                accB[m] = f32x4{0.f, 0.f, 0.f, 0.f};
            }
            if (t + 1 < T_) {
                flag_wait_na<64>(xf, (unsigned)(t + 1));
                gemm_lds2(Xbf + (size_t)nxt * B_ * I_, I_, pbA, pbB, accA, accB, wls);
            }
        }
    } else if (b < 192) {
        // ======== R + Y BLOCKS ============================================
        bf16x8 pbA[12];   // Wxr | Whr
        bf16x8 pbY[8];    // Whq
#pragma unroll
        for (int i = 0; i < 4; ++i)
            pbA[i] = *(const bf16x8*)(WxrT + (size_t)(c16 + l15) * I_ + ((w + (i << 3)) << 5) + q8);
#pragma unroll
        for (int i = 0; i < 8; ++i)
            pbA[4 + i] = *(const bf16x8*)(WhrT + (size_t)(c16 + l15) * H_ + ((w + (i << 3)) << 5) + q8);
        const int yc = (b - 128) << 4;
#pragma unroll
        for (int i = 0; i < 8; ++i)
            pbY[i] = *(const bf16x8*)(WhqT + (size_t)(yc + l15) * H_ + ((w + (i << 3)) << 5) + q8);
        const float br0 = br[c16 + gc], br1 = br[c16 + gc + 1];
        const float bq0 = bhq[yc + gc], bq1 = bhq[yc + gc + 1];

        f32x4 accA[4];
#pragma unroll
        for (int m = 0; m < 4; ++m) accA[m] = f32x4{0.f, 0.f, 0.f, 0.f};
        gemm_lds1<4, 0>(Xbf, I_, pbA, accA, wls);

        for (int t = 0; t < T_; ++t) {
            const int cur = t & 1, nxt = cur ^ 1;
            const __bf16* Hc = Hbf + (size_t)cur * B_ * H_;
            float o2[2];

            // ---- phase A: finish R ----
            flag_wait_na<128>(hnf, (unsigned)t);
            gemm_lds1<8, 4>(Hc, H_, pbA, accA, wls);
            gemm_reduce(accA, red, o2);
            float h0, h1;
            load_h2(Hc + (size_t)gr * H_ + c16 + gc, h0, h1);
            const float rh0 = fsigmoid(o2[0] + br0) * h0;
            const float rh1 = fsigmoid(o2[1] + br1) * h1;

            // ---- WAR guard (usually pre-satisfied), publish RH ----
            flag_wait_na<256>(slots, (unsigned)(t + 1));
            cstore4(RHbf + (size_t)gr * H_ + c16 + gc, pack2bf(rh0, rh1));
            __syncthreads();   // drain RH stores
            if (tid == 0)
                fstore(&rhf[(b - 128) * 16], (unsigned)(t + 1));

            // ---- Y_{t-1} (Hc valid all step) ----
            if (t > 0) {
                f32x4 accY[4];
#pragma unroll
                for (int m = 0; m < 4; ++m) accY[m] = f32x4{0.f, 0.f, 0.f, 0.f};
                gemm_lds1<8, 0>(Hc, H_, pbY, accY, wls);
                gemm_reduce(accY, red, o2);
                f32x2 v;
                v[0] = o2[0] + bq0;
                v[1] = o2[1] + bq1;
                *(f32x2*)(out + ((size_t)(t - 1) * B_ + gr) * I_ + yc + gc) = v;
            }
            __syncthreads();
            if (tid == 0)
                fstore(&slots[b * 16], (unsigned)(t + 2));

            // ---- window: X prefetch for step t+1 ----
#pragma unroll
            for (int m = 0; m < 4; ++m) accA[m] = f32x4{0.f, 0.f, 0.f, 0.f};
            if (t + 1 < T_) {
                flag_wait_na<64>(xf, (unsigned)(t + 1));
                gemm_lds1<4, 0>(Xbf + (size_t)nxt * B_ * I_, I_, pbA, accA, wls);
            }
        }

        // epilogue: Y_{T-1} (H_T in slot (T_ & 1) == 0)
        {
            flag_wait_na<128>(hnf, (unsigned)T_);
            f32x4 accY[4];
#pragma unroll
            for (int m = 0; m < 4; ++m) accY[m] = f32x4{0.f, 0.f, 0.f, 0.f};
            float o2[2];
            gemm_lds1<8, 0>(Hbf, H_, pbY, accY, wls);
            gemm_reduce(accY, red, o2);
            f32x2 v;
            v[0] = o2[0] + bq0;
            v[1] = o2[1] + bq1;
            *(f32x2*)(out + ((size_t)(T_ - 1) * B_ + gr) * I_ + yc + gc) = v;
        }
    } else {
        // ======== R + CONV BLOCKS =========================================
        bf16x8 pbA[12];   // Wxr | Whr
#pragma unroll
        for (int i = 0; i < 4; ++i)
            pbA[i] = *(const bf16x8*)(WxrT + (size_t)(c16 + l15) * I_ + ((w + (i << 3)) << 5) + q8);
#pragma unroll
        for (int i = 0; i < 8; ++i)
            pbA[4 + i] = *(const bf16x8*)(WhrT + (size_t)(c16 + l15) * H_ + ((w + (i << 3)) << 5) + q8);
        const float br0 = br[c16 + gc], br1 = br[c16 + gc + 1];

        f32x4 accA[4];
#pragma unroll
        for (int m = 0; m < 4; ++m) accA[m] = f32x4{0.f, 0.f, 0.f, 0.f};
        gemm_lds1<4, 0>(Xbf, I_, pbA, accA, wls);

        for (int t = 0; t < T_; ++t) {
            const int cur = t & 1, nxt = cur ^ 1;
            const __bf16* Hc = Hbf + (size_t)cur * B_ * H_;
            float o2[2];

            // ---- phase A: finish R ----
            flag_wait_na<128>(hnf, (unsigned)t);
            gemm_lds1<8, 4>(Hc, H_, pbA, accA, wls);
            gemm_reduce(accA, red, o2);
            float h0, h1;
            load_h2(Hc + (size_t)gr * H_ + c16 + gc, h0, h1);
            const float rh0 = fsigmoid(o2[0] + br0) * h0;
            const float rh1 = fsigmoid(o2[1] + br1) * h1;

            // ---- WAR guard, publish RH (rhf BEFORE X conversion) ----
            flag_wait_na<256>(slots, (unsigned)(t + 1));
            cstore4(RHbf + (size_t)gr * H_ + c16 + gc, pack2bf(rh0, rh1));
            __syncthreads();   // drain RH stores
            if (tid == 0)
                fstore(&rhf[(b - 128) * 16], (unsigned)(t + 1));

            // ---- X_{t+1} conversion (WAR covered by slots wait above) ----
            if (t + 1 < T_ && tid < 256) {
                const int idx = (((b - 192) << 8) + tid) << 2;
                f32x4 v = *(const f32x4*)(inputs + (size_t)(t + 1) * B_ * I_ + idx);
                cstore8(Xbf + (size_t)nxt * B_ * I_ + idx,
                        pack4bf(v[0], v[1], v[2], v[3]));
            }
            __syncthreads();   // drain X stores
            if (tid == 0) {
                fstore(&xf[(b - 192) * 16], (unsigned)(t + 1));
                fstore(&slots[b * 16], (unsigned)(t + 2));
            }

            // ---- window: X prefetch for step t+1 ----
#pragma unroll
            for (int m = 0; m < 4; ++m) accA[m] = f32x4{0.f, 0.f, 0.f, 0.f};
            if (t + 1 < T_) {
                flag_wait_na<64>(xf, (unsigned)(t + 1));
                gemm_lds1<4, 0>(Xbf + (size_t)nxt * B_ * I_, I_, pbA, accA, wls);
            }
        }
    }
}

extern "C" void kernel_launch(void* const* d_in, const int* in_sizes, int n_in,
                              void* d_out, int out_size, void* d_ws, size_t ws_size,
                              hipStream_t stream) {
    if (ws_size < WS_NEEDED) return;  // ~41.5 MB scratch required

    const float* inputs = (const float*)d_in[0];
    const float* state  = (const float*)d_in[1];
    const float* Wxz    = (const float*)d_in[2];
    const float* Whz    = (const float*)d_in[3];
    const float* bz     = (const float*)d_in[4];
    const float* Wxr    = (const float*)d_in[5];
    const float* Whr    = (const float*)d_in[6];
    const float* br     = (const float*)d_in[7];
    const float* Wxh    = (const float*)d_in[8];
    const float* Whh    = (const float*)d_in[9];
    const float* bh     = (const float*)d_in[10];
    const float* Whq    = (const float*)d_in[11];
    const float* bhq    = (const float*)d_in[12];

    static bool smem_set = false;
    if (!smem_set) {
        (void)hipFuncSetAttribute((const void*)gru_persistent,
                                  hipFuncAttributeMaxDynamicSharedMemorySize,
                                  (int)SMEM_BYTES);
        smem_set = true;
    }

    hipMemsetAsync(d_ws, 0, 36864, stream);  // slots + hnf + rhf + xf
    gru_persistent<<<NB, NTHREADS, SMEM_BYTES, stream>>>(
        inputs, state, Wxz, Whz, bz, Wxr, Whr, br, Wxh, Whh, bh, Whq, bhq,
        (float*)d_out, (char*)d_ws);
}